// Round 8
// baseline (236.550 us; speedup 1.0000x reference)
//
#include <hip/hip_runtime.h>
#include <hip/hip_bf16.h>

// DecoderLayer cross-attention, MI355X/gfx950. Round 11.
// B=4, Sq=2048, Skv=4096, D=512. fp32 in/out, bf16 MFMA internally.
// R11 changes vs R10 (non-attn = 136us but kernel-work floors sum to ~55us ->
// pipeline glue / cvt round-trip is the suspect):
//  - cvt_all DELETED. proj reads fp32 x/enc/weights directly, converts during
//    reg-staging (reg -> cvt -> ds_write_b128, double-buffered, ONE barrier/step).
//    Swizzle now applied directly on the LDS write address (reg-staging allows it).
//    Saves 13us cvt + 80MB HBM round-trip + 1 launch.
//  - projQ and projKV merged into ONE launch: grid (4,192), blockIdx.y<64 = Q path,
//    else KV dual-output path (block-uniform branch). Saves 1 launch.
//  - attn / reduce byte-identical to R9/R10. Pipeline: proj_all -> attn -> reduce (3 kernels).
// ws layout:
//   Qb  bf16 [8192][512]          @ 0           (8,388,608)
//   Kb  bf16 [16384][512]         @ 8,388,608   (16,777,216)
//   Vtg bf16 [4][128][512][32]    @ 25,165,824  (16,777,216)   (t-tiled)
//   Op  f32 [2][8192][512]        @ 41,943,040  (33,554,432)
//   lp  f32 [2][8192]             @ 75,497,472  (65,536)       need 75,563,008 B

typedef __bf16 bf16;
typedef __attribute__((ext_vector_type(8))) __bf16 bf16x8;
typedef __attribute__((ext_vector_type(4))) float f32x4;

#define DM 512

__device__ __forceinline__ void gload_lds16(const bf16* g, bf16* l)
{
    __builtin_amdgcn_global_load_lds(
        (const __attribute__((address_space(1))) void*)g,
        (__attribute__((address_space(3))) void*)l, 16, 0, 0);
}

// ---------------- Fused projections (fp32 in, cvt in-stage): out = A @ W^T + b -------------
// One launch covers both GEMMs: blockIdx.y < 64 -> Q (x @ wq^T + bq -> Qb row-major);
// else KV dual-output (enc @ wk^T + bk -> Kb row-major; enc @ wv^T + bv -> Vtg t-tiled).
// 128x128 tile, BK=32, 256 threads (4 waves 2x2), double-buffered LDS, reg-staged
// fp32->bf16 convert, 2-bit XOR swizzle on LDS write (read XORs the slot back).
__global__ __launch_bounds__(256, 2) void proj_all_kernel(
    const float* __restrict__ x,   const float* __restrict__ enc,
    const float* __restrict__ wq,  const float* __restrict__ bq,
    const float* __restrict__ wk,  const float* __restrict__ bk,
    const float* __restrict__ wv,  const float* __restrict__ bv,
    bf16* __restrict__ Qb, bf16* __restrict__ Kb, bf16* __restrict__ Vtg)
{
    __shared__ __align__(16) bf16 As[2][128][32];
    __shared__ __align__(16) bf16 W0s[2][128][32];
    __shared__ __align__(16) bf16 W1s[2][128][32];   // used only on KV path

    const int tid  = threadIdx.x;
    const int w    = tid >> 6, lane = tid & 63, quad = lane >> 4, l15 = lane & 15;
    const int wr   = w >> 1, wc = w & 1;
    const int n0   = blockIdx.x * 128;
    const bool isQ = blockIdx.y < 64;
    const int m0   = (isQ ? blockIdx.y : blockIdx.y - 64) * 128;

    const float* A  = isQ ? x  : enc;
    const float* W0 = isQ ? wq : wk;
    const float* B0 = isQ ? bq : bk;

    // staging geometry: lane -> (r = lane>>2 within 16-row segment, cg = lane&3 col-group)
    const int r    = lane >> 2;
    const int cg   = lane & 3;
    const int pcol = (cg ^ (r & 3)) * 8;     // physical LDS col (2-bit XOR swizzle)

    float4 ra[2][2], rw0[2][2], rw1[2][2];

    auto gload = [&](int kk) {
#pragma unroll
        for (int j = 0; j < 2; j++) {
            const int row = 16 * (2*w + j) + r;
            const float* ap = A  + (size_t)(m0 + row) * DM + kk + cg*8;
            const float* wp = W0 + (size_t)(n0 + row) * DM + kk + cg*8;
            ra[j][0]  = *reinterpret_cast<const float4*>(ap);
            ra[j][1]  = *reinterpret_cast<const float4*>(ap + 4);
            rw0[j][0] = *reinterpret_cast<const float4*>(wp);
            rw0[j][1] = *reinterpret_cast<const float4*>(wp + 4);
            if (!isQ) {
                const float* vp = wv + (size_t)(n0 + row) * DM + kk + cg*8;
                rw1[j][0] = *reinterpret_cast<const float4*>(vp);
                rw1[j][1] = *reinterpret_cast<const float4*>(vp + 4);
            }
        }
    };
    auto cvt8 = [](float4 a, float4 b) {
        bf16x8 v;
        v[0]=(bf16)a.x; v[1]=(bf16)a.y; v[2]=(bf16)a.z; v[3]=(bf16)a.w;
        v[4]=(bf16)b.x; v[5]=(bf16)b.y; v[6]=(bf16)b.z; v[7]=(bf16)b.w;
        return v;
    };
    auto lwrite = [&](int p) {
#pragma unroll
        for (int j = 0; j < 2; j++) {
            const int row = 16 * (2*w + j) + r;
            *reinterpret_cast<bf16x8*>(&As[p][row][pcol])  = cvt8(ra[j][0],  ra[j][1]);
            *reinterpret_cast<bf16x8*>(&W0s[p][row][pcol]) = cvt8(rw0[j][0], rw0[j][1]);
            if (!isQ)
                *reinterpret_cast<bf16x8*>(&W1s[p][row][pcol]) = cvt8(rw1[j][0], rw1[j][1]);
        }
    };

    f32x4 acc0[4][4] = {}, acc1[4][4] = {};
    const int sx = l15 & 3;                  // read-side slot XOR (row&3 == l15&3)

    gload(0);
    lwrite(0);
    __syncthreads();

    for (int step = 0; step < 16; step++) {
        const int p = step & 1;
        if (step < 15) gload((step + 1) * 32);   // fp32 loads in flight during compute

        bf16x8 af[4];
#pragma unroll
        for (int mt = 0; mt < 4; mt++)
            af[mt] = *reinterpret_cast<const bf16x8*>(
                &As[p][64*wr + 16*mt + l15][(quad ^ sx) * 8]);
#pragma unroll
        for (int nt = 0; nt < 4; nt++) {
            bf16x8 w0f = *reinterpret_cast<const bf16x8*>(
                &W0s[p][64*wc + 16*nt + l15][(quad ^ sx) * 8]);
#pragma unroll
            for (int mt = 0; mt < 4; mt++)
                acc0[mt][nt] = __builtin_amdgcn_mfma_f32_16x16x32_bf16(af[mt], w0f, acc0[mt][nt], 0, 0, 0);
            if (!isQ) {
                bf16x8 w1f = *reinterpret_cast<const bf16x8*>(
                    &W1s[p][64*wc + 16*nt + l15][(quad ^ sx) * 8]);
#pragma unroll
                for (int mt = 0; mt < 4; mt++)
                    acc1[mt][nt] = __builtin_amdgcn_mfma_f32_16x16x32_bf16(af[mt], w1f, acc1[mt][nt], 0, 0, 0);
            }
        }
        if (step < 15) lwrite(p ^ 1);        // write other buffer (readers of p are done above)
        __syncthreads();                      // publish LDS[p^1] for next step
    }

#pragma unroll
    for (int mt = 0; mt < 4; mt++)
#pragma unroll
        for (int nt = 0; nt < 4; nt++) {
            const int coll = 64*wc + 16*nt + l15;
            const int rowl = 64*wr + 16*mt + quad*4;
            {
                const float bvv = B0[n0 + coll];
                f32x4 c = acc0[mt][nt];
                bf16* out0 = isQ ? Qb : Kb;
#pragma unroll
                for (int rr = 0; rr < 4; rr++)
                    out0[(size_t)(m0 + rowl + rr) * DM + n0 + coll] = (bf16)(c[rr] + bvv);
            }
            if (!isQ) {
                const float bvv = bv[n0 + coll];
                f32x4 c = acc1[mt][nt];
                const int gr = m0 + rowl;
                const int bidx = gr >> 12, t = gr & 4095;
                const int e = n0 + coll;
                union { uint2 u; bf16 h[4]; } pk;
#pragma unroll
                for (int rr = 0; rr < 4; rr++) pk.h[rr] = (bf16)(c[rr] + bvv);
                // t-tiled: Vtg[bidx][t>>5][e][t&31], t % 4 == 0 -> 4 contiguous elems
                *reinterpret_cast<uint2*>(Vtg +
                    ((((size_t)(bidx*128 + (t >> 5)) * DM + e) << 5) + (t & 31))) = pk.u;
            }
        }
}

// ---------------- Fused attention: LDS-K (4-bit swz), reg-Q (16 rows/wave), reg-V ----------
// (byte-identical to R9/R10)
__global__ __launch_bounds__(512, 2) void attn_kernel(const bf16* __restrict__ Qb,
                                                      const bf16* __restrict__ Kb,
                                                      const bf16* __restrict__ Vtg,
                                                      float* __restrict__ Op,
                                                      float* __restrict__ lp)
{
    __shared__ __align__(16) bf16 Kt[2][64][512];   // 131,072 B; 4-bit XOR swizzle (src-side)
    __shared__ __align__(16) bf16 Ps[64][80];       //  10,240 B; 40 dw stride
    __shared__ float lred[64];

    const int tid  = threadIdx.x;
    const int w    = tid >> 6, lane = tid & 63, quad = lane >> 4, l15 = lane & 15;
    const int qb   = w >> 1;                 // QK q-row block 0..3
    const int cb0  = (w & 1) * 2;            // QK kv col blocks {cb0, cb0+1}

    // XCD-swizzle: 8 (b,z) combos map 1:1 onto 8 XCDs.
    const int id = blockIdx.x;               // 256 blocks
    const int combo = id & 7, qblk = id >> 3;
    const int b = combo & 3, z = combo >> 2;
    const int q0 = qblk * 64;
    const int NT = 32, tb = z * 2048;        // 32 tiles of 64 kv rows

    // ---- Q A-fragments into registers (once; 64 VGPR) ----
    bf16x8 af[16];
    {
        const bf16* qsrc = Qb + (size_t)(b*2048 + q0 + 16*qb + l15) * DM + quad*8;
#pragma unroll
        for (int k4 = 0; k4 < 16; k4++) af[k4] = *reinterpret_cast<const bf16x8*>(qsrc + k4*32);
    }
    if (tid < 64) lred[tid] = 0.f;

    const bf16* kbase = Kb + (size_t)(b*4096 + tb) * DM;
    // ---- stage K tile 0 (1 contiguous 1KB row/instr; source lane 4-bit XOR) ----
#pragma unroll
    for (int i = 0; i < 8; i++) {
        const int row = w + 8*i;             // row & 7 == w
        gload_lds16(kbase + (size_t)row * DM + ((lane ^ (row & 15)) * 8), &Kt[0][row][0]);
    }
    __syncthreads();                          // drains DMA, publishes lred

    f32x4 oacc[4][4] = {};
    float lsum[2][4] = {};
    const float kexp = 1.44269504088896f * 0.044194173824159216f;  // log2(e)/sqrt(512)
    const int sxor = l15 << 4;                // read-side 4-bit XOR (rows read have row&15==l15)

    for (int t = 0; t < NT; t++) {
        const int buf = t & 1;

        // V fragments for THIS tile first (oldest vmcnt -> vf-wait leaves K-DMA in flight)
        bf16x8 vf[4][2];
#pragma unroll
        for (int ks = 0; ks < 2; ks++) {
            const size_t tblk = (size_t)(b*128 + z*64 + t*2 + ks) * DM;
#pragma unroll
            for (int nt = 0; nt < 4; nt++)
                vf[nt][ks] = *reinterpret_cast<const bf16x8*>(
                    Vtg + ((tblk + 64*w + 16*nt + l15) << 5) + quad*8);
        }

        // prefetch next K tile (stays in flight until end-of-tile __syncthreads)
        if (t + 1 < NT) {
            const bf16* ksrc = kbase + (size_t)(t + 1) * 64 * DM;
#pragma unroll
            for (int i = 0; i < 8; i++) {
                const int row = w + 8*i;
                gload_lds16(ksrc + (size_t)row * DM + ((lane ^ (row & 15)) * 8), &Kt[buf ^ 1][row][0]);
            }
        }

        // ---- QK: S[16qb..+16][16(cb0..cb0+2)], A regs x B LDS ----
        f32x4 sacc[2] = {};
        const char* krowA = (const char*)&Kt[buf][16*cb0 + l15][0];
        const char* krowB = (const char*)&Kt[buf][16*cb0 + 16 + l15][0];
#pragma unroll
        for (int k4 = 0; k4 < 16; k4++) {
            const int off = (k4*64 + quad*16) ^ sxor;
            bf16x8 k0 = *reinterpret_cast<const bf16x8*>(krowA + off);
            bf16x8 k1 = *reinterpret_cast<const bf16x8*>(krowB + off);
            sacc[0] = __builtin_amdgcn_mfma_f32_16x16x32_bf16(af[k4], k0, sacc[0], 0, 0, 0);
            sacc[1] = __builtin_amdgcn_mfma_f32_16x16x32_bf16(af[k4], k1, sacc[1], 0, 0, 0);
        }

        // exp -> Ps (C-layout -> A-layout), accumulate l
#pragma unroll
        for (int s = 0; s < 2; s++)
#pragma unroll
            for (int r = 0; r < 4; r++) {
                const float p = exp2f(sacc[s][r] * kexp);
                lsum[s][r] += p;
                Ps[16*qb + quad*4 + r][16*(cb0 + s) + l15] = (bf16)p;
            }

        // mid-tile barrier: lgkm-only (Ps is DS traffic; keep K-DMA in flight)
        asm volatile("s_waitcnt lgkmcnt(0)" ::: "memory");
        __builtin_amdgcn_s_barrier();
        __builtin_amdgcn_sched_barrier(0);

        // ---- PV: O[64][64w..+64] += P[64][64] * V[64][...], A LDS x B regs ----
#pragma unroll
        for (int ks = 0; ks < 2; ks++) {
            bf16x8 ap[4];
#pragma unroll
            for (int mt = 0; mt < 4; mt++)
                ap[mt] = *reinterpret_cast<const bf16x8*>(&Ps[16*mt + l15][ks*32 + quad*8]);
#pragma unroll
            for (int nt = 0; nt < 4; nt++)
#pragma unroll
                for (int mt = 0; mt < 4; mt++)
                    oacc[mt][nt] = __builtin_amdgcn_mfma_f32_16x16x32_bf16(ap[mt], vf[nt][ks], oacc[mt][nt], 0, 0, 0);
        }
        __syncthreads();                      // protect Ps + publish K-DMA for next tile
    }

    // ---- epilogue: l reduction + O partial write ----
#pragma unroll
    for (int r = 0; r < 4; r++)
        atomicAdd(&lred[16*qb + quad*4 + r], lsum[0][r] + lsum[1][r]);
    __syncthreads();

    if (tid < 64) lp[(size_t)z * 8192 + b * 2048 + q0 + tid] = lred[tid];
#pragma unroll
    for (int mt = 0; mt < 4; mt++)
#pragma unroll
        for (int r = 0; r < 4; r++) {
            const int row = 16*mt + quad*4 + r;
            float* obase = Op + ((size_t)z * 8192 + b * 2048 + q0 + row) * DM;
#pragma unroll
            for (int nt = 0; nt < 4; nt++)
                obase[64*w + 16*nt + l15] = oacc[mt][nt][r];
        }
}

// ---------------- Combine split partials: out = sum_z Op[z] / sum_z l[z] -------------------
__global__ __launch_bounds__(256) void reduce_kernel(const float* __restrict__ Op,
                                                     const float* __restrict__ lp,
                                                     float* __restrict__ out)
{
    const int g = blockIdx.x * 256 + threadIdx.x;    // 1,048,576 threads x float4
    const size_t e = (size_t)g * 4;
    const int row = g >> 7;
    float4 o = *reinterpret_cast<const float4*>(Op + e);
    float4 a = *reinterpret_cast<const float4*>(Op + 4194304 + e);
    const float l = lp[row] + lp[8192 + row];
    const float linv = 1.0f / l;
    o.x = (o.x + a.x) * linv;
    o.y = (o.y + a.y) * linv;
    o.z = (o.z + a.z) * linv;
    o.w = (o.w + a.w) * linv;
    *reinterpret_cast<float4*>(out + e) = o;
}

extern "C" void kernel_launch(void* const* d_in, const int* in_sizes, int n_in,
                              void* d_out, int out_size, void* d_ws, size_t ws_size,
                              hipStream_t stream)
{
    const float* x   = (const float*)d_in[0];
    const float* enc = (const float*)d_in[1];
    const float* wq  = (const float*)d_in[2];
    const float* bq  = (const float*)d_in[3];
    const float* wk  = (const float*)d_in[4];
    const float* bk  = (const float*)d_in[5];
    const float* wv  = (const float*)d_in[6];
    const float* bv  = (const float*)d_in[7];
    float* out = (float*)d_out;

    char* ws = (char*)d_ws;
    bf16*  Qb   = (bf16*)ws;
    bf16*  Kb   = (bf16*)(ws + 8388608);
    bf16*  Vtg  = (bf16*)(ws + 25165824);
    float* Op   = (float*)(ws + 41943040);
    float* lp   = (float*)(ws + 41943040 + 2ull * 16777216);

    // fused projections (Q tiles: by 0..63; KV tiles: by 64..191), fp32 in, cvt in-stage
    hipLaunchKernelGGL(proj_all_kernel, dim3(4, 192), dim3(256), 0, stream,
                       x, enc, wq, bq, wk, bk, wv, bv, Qb, Kb, Vtg);

    // attention (256 blocks x 512 threads, 1 block/CU) + combine
    hipLaunchKernelGGL(attn_kernel, dim3(256), dim3(512), 0, stream, Qb, Kb, Vtg, Op, lp);
    hipLaunchKernelGGL(reduce_kernel, dim3(4096), dim3(256), 0, stream, Op, lp, out);
}